// Round 2
// baseline (677.399 us; speedup 1.0000x reference)
//
#include <hip/hip_runtime.h>

// S=2048, B=32, H=1024
// out[b][s] = softmax_s( sum_n tanh( (Enc @ We^T)[m][n] + pre_h[b][n] + bias[n] ) * v[n] ),  m = s*32+b

typedef __attribute__((ext_vector_type(8))) short short8;
typedef __attribute__((ext_vector_type(4))) float floatx4;
typedef __attribute__((ext_vector_type(4))) unsigned int uint4v;

#define GLDS(g, l) __builtin_amdgcn_global_load_lds( \
    (const __attribute__((address_space(1))) void*)(g), \
    (__attribute__((address_space(3))) void*)(l), 16, 0, 0)

// round-to-nearest both floats, pack bf16(hi)<<16 | bf16(lo) in ONE v_perm
__device__ __forceinline__ unsigned pack2(float lo, float hi) {
  union { float f; unsigned u; } a, b; a.f = lo; b.f = hi;
  return __builtin_amdgcn_perm(b.u + 0x8000u, a.u + 0x8000u, 0x07060302u);
}

// single-instruction bf16 pair pack: dst = bf16(hi)<<16 | bf16(lo)
__device__ __forceinline__ unsigned cvt_pk(float lo, float hi) {
  unsigned r;
  asm("v_cvt_pk_bf16_f32 %0, %1, %2" : "=v"(r) : "v"(lo), "v"(hi));
  return r;
}

__device__ __forceinline__ float fast_tanh(float x) {
  float e = __expf(2.0f * x);
  return 1.0f - 2.0f / (e + 1.0f);
}

// We (fp32, W[:,1024:2048]) -> bf16 k-chunked layout Bw2[k>>3][n][k&7] in ws.
// Also zeroes scoresT. Grid 512x256, thread -> one (kc, n) pair (8 k-elems).
__global__ __launch_bounds__(256) void k_cvtB(
    const float* __restrict__ W, unsigned int* __restrict__ Bw2,
    float* __restrict__ scoresT) {
  const int idx = blockIdx.x * 256 + threadIdx.x;    // 0..131071
  const int kc = idx >> 10, n = idx & 1023;
  const float* src = W + (size_t)n * 2048 + 1024 + kc * 8;
  float4 f0 = *(const float4*)(src);
  float4 f1 = *(const float4*)(src + 4);
  uint4v u = {pack2(f0.x, f0.y), pack2(f0.z, f0.w),
              pack2(f1.x, f1.y), pack2(f1.z, f1.w)};
  *(uint4v*)(Bw2 + ((size_t)kc * 8192 + n * 8) / 2) = u;   // 16 B, coalesced
  if (idx < 65536) scoresT[idx] = 0.f;
}

// tpre[b][ko] = sum_j hidden[b][j]*W[ko][j] + bias[ko]
__global__ __launch_bounds__(256) void k_preh(
    const float* __restrict__ hidden, const float* __restrict__ W,
    const float* __restrict__ bias, float* __restrict__ tpre) {
  const int g  = blockIdx.x * 256 + threadIdx.x;   // 0..32767
  const int b  = g & 31;
  const int ko = g >> 5;
  const float* wr = W + (size_t)ko * 2048;
  const float* hr = hidden + b * 1024;
  float s = 0.f;
  #pragma unroll 8
  for (int j = 0; j < 1024; j += 4) {
    float4 wv = *(const float4*)(wr + j);     // broadcast within half-wave
    float4 hv = *(const float4*)(hr + j);
    s += wv.x * hv.x + wv.y * hv.y + wv.z * hv.z + wv.w * hv.w;
  }
  tpre[b * 1024 + ko] = s + bias[ko];
}

// MFMA compute on one staged K-tile: 2 k-steps of 32, 16 MFMAs each.
// As layout: [row][64] bf16, 16B-chunks XOR-swizzled by (row&7).
// Bs layout: [kc][128][8] bf16 (GLDS-linear).
__device__ __forceinline__ void mma_tile(const short* __restrict__ Asb,
                                         const short* __restrict__ Bsb,
                                         int wm, int wn, int c, int q,
                                         floatx4 acc[4][4]) {
  #pragma unroll
  for (int ks = 0; ks < 2; ++ks) {
    short8 af[4], bf[4];
    #pragma unroll
    for (int mt = 0; mt < 4; ++mt) {
      const int row = wm * 64 + mt * 16 + c;
      af[mt] = *(const short8*)&Asb[row * 64 + (((ks * 4 + q) ^ (c & 7)) << 3)];
    }
    #pragma unroll
    for (int nt = 0; nt < 4; ++nt)
      bf[nt] = *(const short8*)&Bsb[(ks * 4 + q) * 1024 + (wn * 64 + nt * 16 + c) * 8];
    #pragma unroll
    for (int mt = 0; mt < 4; ++mt)
      #pragma unroll
      for (int nt = 0; nt < 4; ++nt)
        acc[mt][nt] = __builtin_amdgcn_mfma_f32_16x16x32_bf16(
            af[mt], bf[nt], acc[mt][nt], 0, 0, 0);
  }
}

// Fused GEMM + tanh + v-dot. Tile 128(m) x 128(n), BK=64, 4 waves (2x2 of 64x64).
// Counted-vmcnt pipeline (T3/T4): B triple-buffered via GLDS issued 2 iters
// ahead; A reg-staged 1 iter ahead (issue-early / pack-late). Per iteration the
// ONLY waits are s_waitcnt vmcnt(4) + lgkmcnt(0) + raw s_barrier — never a
// vmcnt(0) drain (the round-1 regression was __syncthreads() draining the
// prefetch it was supposed to overlap).
// VMEM ledger per wave/iter (issue order = urgency order):
//   enter: GLDS(t+1) x4 outstanding
//   issue: A(t+1) x8, GLDS(t+2) x4  -> 16 outstanding
//   vmcnt(4): retires GLDS(t+1)+A(t+1); leaves GLDS(t+2)  -> publish + pack ok
__global__ __launch_bounds__(256, 2) void k_gemm(
    const float* __restrict__ A,              // enc [65536][1024] fp32
    const unsigned short* __restrict__ Bw2,   // We bf16 [128 kc][1024 n][8]
    const float* __restrict__ tpre,           // [32][1024]
    const float* __restrict__ vvec,           // [1024]
    float* __restrict__ scoresT) {            // [32][2048], pre-zeroed
  __shared__ short Asf[2 * 128 * 64];         // 2 x 16 KB, swizzled chunks
  __shared__ short Bsf[3 * 8 * 128 * 8];      // 3 x 16 KB  (total 80 KB)

  // XCD swizzle: the 8 n-blocks of one 128-row m-panel share blockIdx%8 -> one XCD
  const int l = blockIdx.x;                   // 4096 blocks
  const int x = l & 7, j = l >> 3;
  const int Mbase = (x * 64 + (j >> 3)) * 128;   // 512 m-panels of 128 rows
  const int Nbase = (j & 7) * 128;

  const int tid = threadIdx.x, lane = tid & 63, w = tid >> 6;
  const int wm = w >> 1, wn = w & 1;
  const int c = lane & 15, q = lane >> 4;

  // A staging: thread -> rows {tid>>2, 64+(tid>>2)}, 16 consecutive k at (tid&3)*16
  const int arow  = tid >> 2;                 // 0..63
  const int ach   = (tid & 3) * 2;            // base 16B-chunk index (0,2,4,6)
  const int acolF = (tid & 3) * 16;
  const float* ap0 = A + (size_t)(Mbase + arow) * 1024 + acolF;
  const float* ap1 = ap0 + 64 * 1024;
  const int sw0 = (ach    ) ^ (arow & 7);     // swizzled chunk indices
  const int sw1 = (ach + 1) ^ (arow & 7);

  // B staging: 16 GLDS of 1 KB; seg = w*4+i -> kc_local = seg>>1, n-half = seg&1
  const unsigned short* bgb = Bw2 + (size_t)(Nbase + lane) * 8;

  floatx4 acc[4][4];
  #pragma unroll
  for (int mt = 0; mt < 4; ++mt)
    #pragma unroll
    for (int nt = 0; nt < 4; ++nt) {
      floatx4 z = {0.f, 0.f, 0.f, 0.f};
      acc[mt][nt] = z;
    }

  int aOffC = 0, aOffN = 128 * 64;            // As buffer offsets (shorts)
  int bOff0 = 0, bOff1 = 8192, bOff2 = 16384; // Bs buffer offsets (shorts)

  // ---- prologue: A(0)->regs, GLDS(0)->buf0, GLDS(1)->buf1; publish buf0 ----
  {
    float4 g[2][4];
    #pragma unroll
    for (int h = 0; h < 2; ++h) {
      const float* ap = h ? ap1 : ap0;
      #pragma unroll
      for (int jj = 0; jj < 4; ++jj) g[h][jj] = *(const float4*)(ap + jj * 4);
    }
    #pragma unroll
    for (int i = 0; i < 4; ++i) {
      const int seg = w * 4 + i, kcl = seg >> 1, half = seg & 1;
      GLDS(bgb + ((size_t)kcl * 8192 + half * 512),
           &Bsf[bOff0 + kcl * 1024 + half * 512]);
    }
    #pragma unroll
    for (int i = 0; i < 4; ++i) {
      const int seg = w * 4 + i, kcl = seg >> 1, half = seg & 1;
      GLDS(bgb + ((size_t)(8 + kcl) * 8192 + half * 512),
           &Bsf[bOff1 + kcl * 1024 + half * 512]);
    }
    // oldest->newest: A(0)x8, GLDS(0)x4, GLDS(1)x4 ; vmcnt(4) -> A(0)+GLDS(0) done
    asm volatile("s_waitcnt vmcnt(4)" ::: "memory");
    #pragma unroll
    for (int h = 0; h < 2; ++h) {
      short* base = &Asf[aOffC + (arow + h * 64) * 64];
      uint4v u0 = {cvt_pk(g[h][0].x, g[h][0].y), cvt_pk(g[h][0].z, g[h][0].w),
                   cvt_pk(g[h][1].x, g[h][1].y), cvt_pk(g[h][1].z, g[h][1].w)};
      uint4v u1 = {cvt_pk(g[h][2].x, g[h][2].y), cvt_pk(g[h][2].z, g[h][2].w),
                   cvt_pk(g[h][3].x, g[h][3].y), cvt_pk(g[h][3].z, g[h][3].w)};
      *(uint4v*)&base[sw0 << 3] = u0;
      *(uint4v*)&base[sw1 << 3] = u1;
    }
    asm volatile("s_waitcnt lgkmcnt(0)" ::: "memory");
    __builtin_amdgcn_s_barrier();
    asm volatile("" ::: "memory");
  }

  for (int t = 0; t < 15; ++t) {
    const int k1 = (t + 1) * 64;

    // ---- issue A(t+1) (oldest = consumed this iter at pack) ----
    float4 g[2][4];
    #pragma unroll
    for (int h = 0; h < 2; ++h) {
      const float* ap = h ? ap1 : ap0;
      #pragma unroll
      for (int jj = 0; jj < 4; ++jj) g[h][jj] = *(const float4*)(ap + k1 + jj * 4);
    }
    // ---- issue GLDS B(t+2) -> bOff2 (newest = consumed in 2 iters) ----
    if (t <= 13) {
      const int k2 = (t + 2) * 64;
      #pragma unroll
      for (int i = 0; i < 4; ++i) {
        const int seg = w * 4 + i, kcl = seg >> 1, half = seg & 1;
        GLDS(bgb + ((size_t)((k2 >> 3) + kcl) * 8192 + half * 512),
             &Bsf[bOff2 + kcl * 1024 + half * 512]);
      }
    }

    // ---- compute current tile: 32 MFMA / wave ----
    mma_tile(&Asf[aOffC], &Bsf[bOff0], wm, wn, c, q, acc);

    // ---- counted wait: A(t+1)+GLDS(t+1) retired, GLDS(t+2) stays in flight ----
    if (t <= 13) asm volatile("s_waitcnt vmcnt(4)" ::: "memory");
    else         asm volatile("s_waitcnt vmcnt(0)" ::: "memory");

    // ---- pack + write A(t+1) (write-late) ----
    #pragma unroll
    for (int h = 0; h < 2; ++h) {
      short* base = &Asf[aOffN + (arow + h * 64) * 64];
      uint4v u0 = {cvt_pk(g[h][0].x, g[h][0].y), cvt_pk(g[h][0].z, g[h][0].w),
                   cvt_pk(g[h][1].x, g[h][1].y), cvt_pk(g[h][1].z, g[h][1].w)};
      uint4v u1 = {cvt_pk(g[h][2].x, g[h][2].y), cvt_pk(g[h][2].z, g[h][2].w),
                   cvt_pk(g[h][3].x, g[h][3].y), cvt_pk(g[h][3].z, g[h][3].w)};
      *(uint4v*)&base[sw0 << 3] = u0;
      *(uint4v*)&base[sw1 << 3] = u1;
    }
    asm volatile("s_waitcnt lgkmcnt(0)" ::: "memory");
    __builtin_amdgcn_s_barrier();
    asm volatile("" ::: "memory");

    // rotate buffers
    int ta = aOffC; aOffC = aOffN; aOffN = ta;
    int tb = bOff0; bOff0 = bOff1; bOff1 = bOff2; bOff2 = tb;
  }
  mma_tile(&Asf[aOffC], &Bsf[bOff0], wm, wn, c, q, acc);   // tail tile (t=15)

  // Epilogue: score[m] += sum_n tanh(pre_e + tpre[b][n]) * v[n]
  // C layout: col = lane&15, row = (lane>>4)*4 + i
  const int mwave = Mbase + wm * 64;
  const int nwave = Nbase + wn * 64;
  float vv[4];
  #pragma unroll
  for (int nt = 0; nt < 4; ++nt) vv[nt] = vvec[nwave + nt * 16 + c];
  #pragma unroll
  for (int mt = 0; mt < 4; ++mt) {
    #pragma unroll
    for (int i = 0; i < 4; ++i) {
      const int mrow = mwave + mt * 16 + q * 4 + i;
      const float* tb = tpre + (mrow & 31) * 1024;
      float ssum = 0.f;
      #pragma unroll
      for (int nt = 0; nt < 4; ++nt) {
        float pre = acc[mt][nt][i] + tb[nwave + nt * 16 + c];
        ssum += fast_tanh(pre) * vv[nt];
      }
      #pragma unroll
      for (int off = 1; off < 16; off <<= 1) ssum += __shfl_xor(ssum, off, 64);
      if (c == 0) atomicAdd(&scoresT[(mrow & 31) * 2048 + (mrow >> 5)], ssum);
    }
  }
}

// softmax over s for each b: scoresT[b][s] -> out[b][s]  (coalesced)
__global__ __launch_bounds__(256) void k_softmax(
    const float* __restrict__ scoresT, float* __restrict__ out) {
  const int b = blockIdx.x;
  const int t = threadIdx.x;
  const int w = t >> 6, lane = t & 63;
  __shared__ float red[4];
  float vals[8];
  float m = -3.0e38f;
  #pragma unroll
  for (int i = 0; i < 8; ++i) {
    vals[i] = scoresT[b * 2048 + t + 256 * i];
    m = fmaxf(m, vals[i]);
  }
  #pragma unroll
  for (int off = 32; off; off >>= 1) m = fmaxf(m, __shfl_xor(m, off, 64));
  if (lane == 0) red[w] = m;
  __syncthreads();
  m = fmaxf(fmaxf(red[0], red[1]), fmaxf(red[2], red[3]));
  __syncthreads();
  float e[8];
  float sum = 0.f;
  #pragma unroll
  for (int i = 0; i < 8; ++i) { e[i] = __expf(vals[i] - m); sum += e[i]; }
  #pragma unroll
  for (int off = 32; off; off >>= 1) sum += __shfl_xor(sum, off, 64);
  if (lane == 0) red[w] = sum;
  __syncthreads();
  sum = red[0] + red[1] + red[2] + red[3];
  const float inv = 1.0f / sum;
  #pragma unroll
  for (int i = 0; i < 8; ++i) out[b * 2048 + t + 256 * i] = e[i] * inv;
}

extern "C" void kernel_launch(void* const* d_in, const int* in_sizes, int n_in,
                              void* d_out, int out_size, void* d_ws, size_t ws_size,
                              hipStream_t stream) {
  const float* hidden = (const float*)d_in[0];   // (1,32,1024)
  const float* enc    = (const float*)d_in[1];   // (2048,32,1024)
  const float* W      = (const float*)d_in[2];   // (1024,2048)
  const float* bias   = (const float*)d_in[3];   // (1024,)
  const float* vvec   = (const float*)d_in[4];   // (1024,)
  float* out = (float*)d_out;                    // (32,1,2048) fp32

  float* scoresT = (float*)d_ws;                          // 65536 fp32
  float* tpre    = scoresT + 65536;                       // 32768 fp32
  unsigned int* Bw2 = (unsigned int*)(tpre + 32768);      // 1M bf16 = 2 MB

  hipLaunchKernelGGL(k_cvtB, dim3(512), dim3(256), 0, stream, W, Bw2, scoresT);
  hipLaunchKernelGGL(k_preh, dim3(128), dim3(256), 0, stream, hidden, W, bias, tpre);
  hipLaunchKernelGGL(k_gemm, dim3(4096), dim3(256), 0, stream,
                     enc, (const unsigned short*)Bw2, tpre, vvec, scoresT);
  hipLaunchKernelGGL(k_softmax, dim3(32), dim3(256), 0, stream, scoresT, out);
}

// Round 3
// 609.367 us; speedup vs baseline: 1.1116x; 1.1116x over previous
//
#include <hip/hip_runtime.h>

// S=2048, B=32, H=1024
// out[b][s] = softmax_s( sum_n tanh( (Enc @ We^T)[m][n] + pre_h[b][n] + bias[n] ) * v[n] ),  m = s*32+b

typedef __attribute__((ext_vector_type(8))) short short8;
typedef __attribute__((ext_vector_type(4))) float floatx4;
typedef __attribute__((ext_vector_type(4))) unsigned int uint4v;

#define GLDS(g, l) __builtin_amdgcn_global_load_lds( \
    (const __attribute__((address_space(1))) void*)(g), \
    (__attribute__((address_space(3))) void*)(l), 16, 0, 0)

// round-to-nearest both floats, pack bf16(hi)<<16 | bf16(lo) in ONE v_perm
__device__ __forceinline__ unsigned pack2(float lo, float hi) {
  union { float f; unsigned u; } a, b; a.f = lo; b.f = hi;
  return __builtin_amdgcn_perm(b.u + 0x8000u, a.u + 0x8000u, 0x07060302u);
}

// single-instruction bf16 pair pack (RNE): dst = bf16(hi)<<16 | bf16(lo)
__device__ __forceinline__ unsigned cvt_pk(float lo, float hi) {
  unsigned r;
  asm("v_cvt_pk_bf16_f32 %0, %1, %2" : "=v"(r) : "v"(lo), "v"(hi));
  return r;
}

__device__ __forceinline__ float fast_tanh(float x) {
  float e = __expf(2.0f * x);
  return 1.0f - 2.0f / (e + 1.0f);
}

// We (fp32, W[:,1024:2048]) -> bf16 k-chunked layout Bw2[k>>3][n][k&7] in ws.
// Also zeroes scoresT. Grid 512x256, thread -> one (kc, n) pair (8 k-elems).
__global__ __launch_bounds__(256) void k_cvtB(
    const float* __restrict__ W, unsigned int* __restrict__ Bw2,
    float* __restrict__ scoresT) {
  const int idx = blockIdx.x * 256 + threadIdx.x;    // 0..131071
  const int kc = idx >> 10, n = idx & 1023;
  const float* src = W + (size_t)n * 2048 + 1024 + kc * 8;
  float4 f0 = *(const float4*)(src);
  float4 f1 = *(const float4*)(src + 4);
  uint4v u = {pack2(f0.x, f0.y), pack2(f0.z, f0.w),
              pack2(f1.x, f1.y), pack2(f1.z, f1.w)};
  *(uint4v*)(Bw2 + ((size_t)kc * 8192 + n * 8) / 2) = u;   // 16 B, coalesced
  if (idx < 65536) scoresT[idx] = 0.f;
}

// tpre[b][ko] = sum_j hidden[b][j]*W[ko][j] + bias[ko]
__global__ __launch_bounds__(256) void k_preh(
    const float* __restrict__ hidden, const float* __restrict__ W,
    const float* __restrict__ bias, float* __restrict__ tpre) {
  const int g  = blockIdx.x * 256 + threadIdx.x;   // 0..32767
  const int b  = g & 31;
  const int ko = g >> 5;
  const float* wr = W + (size_t)ko * 2048;
  const float* hr = hidden + b * 1024;
  float s = 0.f;
  #pragma unroll 8
  for (int j = 0; j < 1024; j += 4) {
    float4 wv = *(const float4*)(wr + j);     // broadcast within half-wave
    float4 hv = *(const float4*)(hr + j);
    s += wv.x * hv.x + wv.y * hv.y + wv.z * hv.z + wv.w * hv.w;
  }
  tpre[b * 1024 + ko] = s + bias[ko];
}

// Fused GEMM + tanh + v-dot. Tile 64(m) x 128(n), BK=64, 4 waves (2x2 of 32x64).
// Round-0 TLP regime (single buffer, 2 barriers/iter, 5 blocks/CU) with the
// stage path fixed: BOTH A and B staged via global_load_lds (no VGPR round
// trip, no pack VALU at stage). A kept fp32 in LDS; fp32->bf16 conversion at
// fragment read (16 cvt_pk / wave / iter).
// As layout: [row][chunk] of 16B fp32 chunks, content swizzled chunk^=(row&15)
// via per-lane pre-swizzled GLDS SOURCE addresses (linear LDS dest, rule #21).
// Fragment row r = wm*32+mt*16+c has r&15 == c, so 16 c-lanes hit 16 distinct
// chunks -> 2-way bank aliasing = free.
__global__ __launch_bounds__(256, 5) void k_gemm(
    const float* __restrict__ A,              // enc [65536][1024] fp32
    const unsigned short* __restrict__ Bw2,   // We bf16 [128 kc][1024 n][8]
    const float* __restrict__ tpre,           // [32][1024]
    const float* __restrict__ vvec,           // [1024]
    float* __restrict__ scoresT) {            // [32][2048], pre-zeroed
  __shared__ float As[64 * 64];               // [row][16 chunks of 4 fp32] = 16 KB
  __shared__ short Bs[8 * 128 * 8];           // [kc][n][8] = 16 KB (total 32 KB)

  // XCD swizzle: the 8 n-blocks of one 64-row m-panel share blockIdx%8 -> one XCD
  const int l = blockIdx.x;                   // 8192 blocks
  const int x = l & 7, j = l >> 3;
  const int Mbase = (x * 128 + (j >> 3)) * 64;   // 1024 m-panels of 64 rows
  const int Nbase = (j & 7) * 128;

  const int tid = threadIdx.x, lane = tid & 63, w = tid >> 6;
  const int wm = w >> 1, wn = w & 1;
  const int c = lane & 15, q = lane >> 4;

  // A staging: 4 GLDS per wave; instr g covers rows w*16+g*4 .. +3 (4 rows x 256B).
  // lane -> row = w*16 + g*4 + (lane>>4), dest chunk = lane&15 (linear dest).
  // source chunk = (lane&15) ^ (row & 15)  [w*16 drops out of the &15]
  const int rg = lane >> 4;                   // 0..3 row-within-instr
  const float* aps[4];
  #pragma unroll
  for (int g = 0; g < 4; ++g) {
    const int rlow = (g * 4 + rg) & 15;
    const int schunk = (lane & 15) ^ rlow;
    aps[g] = A + (size_t)(Mbase + w * 16 + g * 4 + rg) * 1024 + schunk * 4;
  }

  // B staging: 4 GLDS of 1 KB per wave; seg = w*4+i -> kc_local = seg>>1, n-half = seg&1
  const unsigned short* bgb = Bw2 + (size_t)(Nbase + lane) * 8;

  floatx4 acc[2][4];
  #pragma unroll
  for (int mt = 0; mt < 2; ++mt)
    #pragma unroll
    for (int nt = 0; nt < 4; ++nt) {
      floatx4 z = {0.f, 0.f, 0.f, 0.f};
      acc[mt][nt] = z;
    }

  for (int k0 = 0; k0 < 1024; k0 += 64) {
    // ---- stage: pure GLDS issue, no reg staging ----
    #pragma unroll
    for (int g = 0; g < 4; ++g)
      GLDS(aps[g] + k0, &As[(w * 16 + g * 4) * 64]);
    #pragma unroll
    for (int i = 0; i < 4; ++i) {
      const int seg = w * 4 + i, kcl = seg >> 1, half = seg & 1;
      GLDS(bgb + ((size_t)((k0 >> 3) + kcl) * 8192 + half * 512),
           &Bs[kcl * 1024 + half * 512]);
    }
    __syncthreads();                       // staging visible (vmcnt drain; TLP covers)

    // ---- compute: 2 k-steps of 32, 8 MFMAs each ----
    #pragma unroll
    for (int ks = 0; ks < 2; ++ks) {
      short8 af[2], bf[4];
      #pragma unroll
      for (int mt = 0; mt < 2; ++mt) {
        const int r = wm * 32 + mt * 16 + c;     // r&15 == c
        const int c0 = ks * 8 + q * 2;           // global fp32-chunk (even)
        const float4 lo = *(const float4*)&As[r * 64 + ((c0    ) ^ c) * 4];
        const float4 hi = *(const float4*)&As[r * 64 + ((c0 + 1) ^ c) * 4];
        uint4v ua = {cvt_pk(lo.x, lo.y), cvt_pk(lo.z, lo.w),
                     cvt_pk(hi.x, hi.y), cvt_pk(hi.z, hi.w)};
        af[mt] = *(short8*)&ua;
      }
      #pragma unroll
      for (int nt = 0; nt < 4; ++nt)
        bf[nt] = *(const short8*)&Bs[(ks * 4 + q) * 1024 + (wn * 64 + nt * 16 + c) * 8];
      #pragma unroll
      for (int mt = 0; mt < 2; ++mt)
        #pragma unroll
        for (int nt = 0; nt < 4; ++nt)
          acc[mt][nt] = __builtin_amdgcn_mfma_f32_16x16x32_bf16(
              af[mt], bf[nt], acc[mt][nt], 0, 0, 0);
    }
    __syncthreads();                       // frag reads done before next stage
  }

  // Epilogue: score[m] += sum_n tanh(pre_e + tpre[b][n]) * v[n]
  // C layout: col = lane&15, row = (lane>>4)*4 + i
  const int mwave = Mbase + wm * 32;
  const int nwave = Nbase + wn * 64;
  float vv[4];
  #pragma unroll
  for (int nt = 0; nt < 4; ++nt) vv[nt] = vvec[nwave + nt * 16 + c];
  #pragma unroll
  for (int mt = 0; mt < 2; ++mt) {
    #pragma unroll
    for (int i = 0; i < 4; ++i) {
      const int mrow = mwave + mt * 16 + q * 4 + i;
      const float* tb = tpre + (mrow & 31) * 1024;
      float ssum = 0.f;
      #pragma unroll
      for (int nt = 0; nt < 4; ++nt) {
        float pre = acc[mt][nt][i] + tb[nwave + nt * 16 + c];
        ssum += fast_tanh(pre) * vv[nt];
      }
      #pragma unroll
      for (int off = 1; off < 16; off <<= 1) ssum += __shfl_xor(ssum, off, 64);
      if (c == 0) atomicAdd(&scoresT[(mrow & 31) * 2048 + (mrow >> 5)], ssum);
    }
  }
}

// softmax over s for each b: scoresT[b][s] -> out[b][s]  (coalesced)
__global__ __launch_bounds__(256) void k_softmax(
    const float* __restrict__ scoresT, float* __restrict__ out) {
  const int b = blockIdx.x;
  const int t = threadIdx.x;
  const int w = t >> 6, lane = t & 63;
  __shared__ float red[4];
  float vals[8];
  float m = -3.0e38f;
  #pragma unroll
  for (int i = 0; i < 8; ++i) {
    vals[i] = scoresT[b * 2048 + t + 256 * i];
    m = fmaxf(m, vals[i]);
  }
  #pragma unroll
  for (int off = 32; off; off >>= 1) m = fmaxf(m, __shfl_xor(m, off, 64));
  if (lane == 0) red[w] = m;
  __syncthreads();
  m = fmaxf(fmaxf(red[0], red[1]), fmaxf(red[2], red[3]));
  __syncthreads();
  float e[8];
  float sum = 0.f;
  #pragma unroll
  for (int i = 0; i < 8; ++i) { e[i] = __expf(vals[i] - m); sum += e[i]; }
  #pragma unroll
  for (int off = 32; off; off >>= 1) sum += __shfl_xor(sum, off, 64);
  if (lane == 0) red[w] = sum;
  __syncthreads();
  sum = red[0] + red[1] + red[2] + red[3];
  const float inv = 1.0f / sum;
  #pragma unroll
  for (int i = 0; i < 8; ++i) out[b * 2048 + t + 256 * i] = e[i] * inv;
}

extern "C" void kernel_launch(void* const* d_in, const int* in_sizes, int n_in,
                              void* d_out, int out_size, void* d_ws, size_t ws_size,
                              hipStream_t stream) {
  const float* hidden = (const float*)d_in[0];   // (1,32,1024)
  const float* enc    = (const float*)d_in[1];   // (2048,32,1024)
  const float* W      = (const float*)d_in[2];   // (1024,2048)
  const float* bias   = (const float*)d_in[3];   // (1024,)
  const float* vvec   = (const float*)d_in[4];   // (1024,)
  float* out = (float*)d_out;                    // (32,1,2048) fp32

  float* scoresT = (float*)d_ws;                          // 65536 fp32
  float* tpre    = scoresT + 65536;                       // 32768 fp32
  unsigned int* Bw2 = (unsigned int*)(tpre + 32768);      // 1M bf16 = 2 MB

  hipLaunchKernelGGL(k_cvtB, dim3(512), dim3(256), 0, stream, W, Bw2, scoresT);
  hipLaunchKernelGGL(k_preh, dim3(128), dim3(256), 0, stream, hidden, W, bias, tpre);
  hipLaunchKernelGGL(k_gemm, dim3(8192), dim3(256), 0, stream,
                     enc, (const unsigned short*)Bw2, tpre, vvec, scoresT);
  hipLaunchKernelGGL(k_softmax, dim3(32), dim3(256), 0, stream, scoresT, out);
}